// Round 6
// baseline (276.316 us; speedup 1.0000x reference)
//
#include <hip/hip_runtime.h>
#include <hip/hip_bf16.h>

// ---------- types / helpers ----------
typedef __attribute__((ext_vector_type(8))) short bf16x8;   // 8 bf16 = 4 VGPRs
typedef __attribute__((ext_vector_type(4))) short bf16x4;
typedef __attribute__((ext_vector_type(4))) float f32x4;

__device__ __forceinline__ short f2bf(float f) {
    unsigned u = __float_as_uint(f);
    u += 0x7fff + ((u >> 16) & 1);          // round-to-nearest-even
    return (short)(u >> 16);
}
__device__ __forceinline__ float bf2f(short s) {
    return __uint_as_float(((unsigned)(unsigned short)s) << 16);
}
// pack two floats -> bf16x2 dword (v_cvt_pk_bf16_f32 on gfx950)
__device__ __forceinline__ unsigned pk_bf16(float lo, float hi) {
    __hip_bfloat162 t = __float22bfloat162_rn(make_float2(lo, hi));
    unsigned u;
    __builtin_memcpy(&u, &t, 4);
    return u;
}

#define GLOAD_LDS16(gp, lp)                                                            \
    __builtin_amdgcn_global_load_lds(                                                  \
        (const __attribute__((address_space(1))) unsigned*)(gp),                       \
        (__attribute__((address_space(3))) unsigned*)(lp), 16, 0, 0)

#define QK_SCALE 0.180336879f   // (1/sqrt(64)) * log2(e), folded into q at GEMM1

// ---------- fused prep: enc->bf16, biases->bf16, Wa/Wo -> transposed bf16 ----------
__device__ __forceinline__ void tcvt_tile(const float* __restrict__ W, short* __restrict__ Wt,
                                          int K, int N, int bx, int by, int t,
                                          short (*tile)[72]) {
    const int k0 = by * 64, n0 = bx * 64;
    #pragma unroll
    for (int jj = 0; jj < 4; ++jj) {
        int row = jj * 16 + (t >> 4);
        int col = (t & 15) * 4;
        f32x4 v = *(const f32x4*)&W[(size_t)(k0 + row) * N + n0 + col];
        bf16x4 b = {f2bf(v.x), f2bf(v.y), f2bf(v.z), f2bf(v.w)};
        *(bf16x4*)&tile[row][col] = b;
    }
    __syncthreads();
    const int nr = t >> 2, kc = (t & 3) * 16;
    bf16x8 o0, o1;
    #pragma unroll
    for (int j = 0; j < 8; ++j) { o0[j] = tile[kc + j][nr]; o1[j] = tile[kc + 8 + j][nr]; }
    short* dst = &Wt[(size_t)(n0 + nr) * K + k0 + kc];
    *(bf16x8*)dst = o0;
    *(bf16x8*)(dst + 8) = o1;
}

__global__ __launch_bounds__(256) void prep_kernel(
    const float* __restrict__ enc, const float* __restrict__ Wa,
    const float* __restrict__ ba, const float* __restrict__ Wo,
    const float* __restrict__ bo, short* __restrict__ Abf,
    short* __restrict__ WtA, short* __restrict__ bbA,
    short* __restrict__ WtO, short* __restrict__ bbO)
{
    __shared__ alignas(16) short tile[64][72];
    const int id = blockIdx.x, t = threadIdx.x;
    if (id < 2048) {
        const int i = id * 2048 + t * 8;
        f32x4 a = *(const f32x4*)&enc[i];
        f32x4 b = *(const f32x4*)&enc[i + 4];
        bf16x8 o = {f2bf(a.x), f2bf(a.y), f2bf(a.z), f2bf(a.w),
                    f2bf(b.x), f2bf(b.y), f2bf(b.z), f2bf(b.w)};
        *(bf16x8*)&Abf[i] = o;
    } else if (id == 2048) {
        for (int j = t * 8; j < 3072; j += 2048) {
            f32x4 a = *(const f32x4*)&ba[j];
            f32x4 b = *(const f32x4*)&ba[j + 4];
            bf16x8 o = {f2bf(a.x), f2bf(a.y), f2bf(a.z), f2bf(a.w),
                        f2bf(b.x), f2bf(b.y), f2bf(b.z), f2bf(b.w)};
            *(bf16x8*)&bbA[j] = o;
        }
    } else if (id == 2049) {
        if (t < 128) {
            const int j = t * 8;
            f32x4 a = *(const f32x4*)&bo[j];
            f32x4 b = *(const f32x4*)&bo[j + 4];
            bf16x8 o = {f2bf(a.x), f2bf(a.y), f2bf(a.z), f2bf(a.w),
                        f2bf(b.x), f2bf(b.y), f2bf(b.z), f2bf(b.w)};
            *(bf16x8*)&bbO[j] = o;
        }
        __syncthreads();
    } else if (id < 2818) {
        const int lid = id - 2050;
        tcvt_tile(Wa, WtA, 1024, 3072, lid % 48, lid / 48, t, tile);
    } else {
        const int lid = id - 2818;
        tcvt_tile(Wo, WtO, 1024, 1024, lid % 16, lid / 16, t, tile);
    }
}

// ---------- bf16 V slab -> per-head transposed Vt[bh][d][seq] ----------
__global__ __launch_bounds__(256) void vtrans_kernel(const short* __restrict__ qkv,
                                                     short* __restrict__ Vt) {
    __shared__ alignas(16) short T[64][72];
    const int t = threadIdx.x;
    const int seq0 = blockIdx.x * 64;
    const int bh = blockIdx.y, batch = bh >> 4, head = bh & 15;
    #pragma unroll
    for (int jj = 0; jj < 2; ++jj) {
        const int seqr = jj * 32 + (t >> 3);
        const int dcol = (t & 7) * 8;
        bf16x8 v = *(const bf16x8*)&qkv[(size_t)(batch * 2048 + seq0 + seqr) * 3072
                                        + 2048 + head * 64 + dcol];
        #pragma unroll
        for (int j = 0; j < 8; ++j) T[dcol + j][seqr] = v[j];
    }
    __syncthreads();
    #pragma unroll
    for (int jj = 0; jj < 2; ++jj) {
        const int d = jj * 32 + (t >> 3);
        const int sp = (t & 7) * 8;
        bf16x8 v = *(const bf16x8*)&T[d][sp];
        *(bf16x8*)&Vt[((size_t)(batch * 16 + head) * 64 + d) * 2048 + seq0 + sp] = v;
    }
}

// ---------- m97-style BT GEMM: C[M,N] = A[M,K] @ Bt[N,K]^T + bias ----------
template<int BN, bool F32OUT, bool QSCALE>
__global__ __launch_bounds__(256) void gemm_bt(
    const short* __restrict__ A, const short* __restrict__ Bt,
    const short* __restrict__ bias, void* __restrict__ C, int M, int N, int K)
{
    __shared__ alignas(16) short As[128 * 32];
    __shared__ alignas(16) short Bs[BN * 32];

    const int tid = threadIdx.x, w = tid >> 6, lane = tid & 63;
    const int quad = lane >> 4, l16 = lane & 15;
    constexpr int MT = (BN == 128) ? 4 : 2;
    const int wm = (BN == 128) ? (w >> 1) : w;
    const int wn = (BN == 128) ? (w & 1) : 0;
    const int m0 = blockIdx.y * 128, n0 = blockIdx.x * BN;
    const int srow = lane >> 2, scol = (lane & 3) * 8;

    f32x4 acc[MT][4] = {};

    for (int k0 = 0; k0 < K; k0 += 32) {
        __syncthreads();
        #pragma unroll
        for (int jj = 0; jj < 2; ++jj) {
            const int rb = w * 32 + jj * 16;
            GLOAD_LDS16(&A[(size_t)(m0 + rb + srow) * K + k0 + scol], &As[rb * 32]);
        }
        if (BN == 128) {
            #pragma unroll
            for (int jj = 0; jj < 2; ++jj) {
                const int rb = w * 32 + jj * 16;
                GLOAD_LDS16(&Bt[(size_t)(n0 + rb + srow) * K + k0 + scol], &Bs[rb * 32]);
            }
        } else {
            const int rb = w * 16;
            GLOAD_LDS16(&Bt[(size_t)(n0 + rb + srow) * K + k0 + scol], &Bs[rb * 32]);
        }
        __syncthreads();
        bf16x8 af[MT], bfr[4];
        #pragma unroll
        for (int i = 0; i < MT; ++i)
            af[i] = *(const bf16x8*)&As[(wm * (MT * 16) + i * 16 + l16) * 32 + quad * 8];
        #pragma unroll
        for (int i = 0; i < 4; ++i)
            bfr[i] = *(const bf16x8*)&Bs[(wn * 64 + i * 16 + l16) * 32 + quad * 8];
        #pragma unroll
        for (int mt = 0; mt < MT; ++mt)
            #pragma unroll
            for (int nt = 0; nt < 4; ++nt)
                acc[mt][nt] = __builtin_amdgcn_mfma_f32_16x16x32_bf16(af[mt], bfr[nt], acc[mt][nt], 0, 0, 0);
    }

    #pragma unroll
    for (int nt = 0; nt < 4; ++nt) {
        const int col = n0 + wn * 64 + nt * 16 + l16;
        const float bv = bf2f(bias[col]);
        const bool qs = QSCALE && (col < 1024);
        #pragma unroll
        for (int mt = 0; mt < MT; ++mt) {
            const int row = m0 + wm * (MT * 16) + mt * 16 + quad * 4;
            #pragma unroll
            for (int r = 0; r < 4; ++r) {
                float v = acc[mt][nt][r] + bv;
                if (qs) v *= QK_SCALE;
                if (F32OUT) ((float*)C)[(size_t)(row + r) * N + col] = v;
                else        ((short*)C)[(size_t)(row + r) * N + col] = f2bf(v);
            }
        }
    }
}

// ---------- barrier-free causal flash attention (S^T formulation) ----------
// S^T = K.Q^T (A=K, B=Q): C-layout holds key=quad*4+r (+16s), q=l16 -> the P^T
// B-operand for O^T = V^T.P^T packs as 8 dword LDS writes + 2 b128 reads.
// l-sum is a scalar per lane (one q each). One q-tile (64 rows) per block;
// grid (32 bh, 32 y), p = 31-y (LPT: heaviest first). Natural VGPR (no cap).
__global__ __launch_bounds__(256) void attn_kernel(
    const short* __restrict__ qkv, const short* __restrict__ Vt, short* __restrict__ comb)
{
    __shared__ alignas(16) short Ps[4][16 * 72];   // per-wave P^T buffer [q][key(+pad)]

    const int tid = threadIdx.x, w = tid >> 6, lane = tid & 63;
    const int quad = lane >> 4, l16 = lane & 15;
    const int bh = blockIdx.x;
    const int p = 31 - blockIdx.y;                 // LPT order
    const int batch = bh >> 4, head = bh & 15;
    const size_t rowbase = (size_t)batch * 2048;
    const int hcol = head * 64;
    const int q0 = p * 64 + w * 16;
    const short* Vbase = Vt + (size_t)bh * 64 * 2048;

    // Q as B-operand: B[k=d][n=q], lane: q=l16, d=quad*8+j (+32)
    bf16x8 qf[2];
    {
        const short* qp = &qkv[(rowbase + q0 + l16) * 3072 + hcol];
        qf[0] = *(const bf16x8*)(qp + quad * 8);
        qf[1] = *(const bf16x8*)(qp + 32 + quad * 8);
    }

    f32x4 ot[4] = {};          // O^T: ot[dt], d = dt*16+quad*4+r, q = l16
    float lacc = 0.f;          // sum over keys for q = q0+l16
    short* pw = &Ps[w][0];     // row stride 72 shorts (144 B, 16B-aligned)

    auto tile_step = [&](int kc, bool diag) {
        const int key0 = kc * 64;
        // K as A-operand: A[m=key][k=d]
        bf16x8 kf[4][2];
        #pragma unroll
        for (int s = 0; s < 4; ++s) {
            const short* kp = &qkv[(rowbase + key0 + s * 16 + l16) * 3072 + 1024 + hcol + quad * 8];
            kf[s][0] = *(const bf16x8*)kp;
            kf[s][1] = *(const bf16x8*)(kp + 32);
        }
        // V^T as A-operand: A[m=d][k=key]
        bf16x8 vf[2][4];
        #pragma unroll
        for (int h = 0; h < 2; ++h)
            #pragma unroll
            for (int dt = 0; dt < 4; ++dt)
                vf[h][dt] = *(const bf16x8*)&Vbase[(size_t)(dt * 16 + l16) * 2048 + key0 + h * 32 + quad * 8];

        // S^T subtiles: key = key0 + s*16 + quad*4 + r, q = q0 + l16
        f32x4 sv[4];
        #pragma unroll
        for (int s = 0; s < 4; ++s) {
            f32x4 a = {0.f, 0.f, 0.f, 0.f};
            a = __builtin_amdgcn_mfma_f32_16x16x32_bf16(kf[s][0], qf[0], a, 0, 0, 0);
            a = __builtin_amdgcn_mfma_f32_16x16x32_bf16(kf[s][1], qf[1], a, 0, 0, 0);
            sv[s] = a;
        }

        if (diag) {
            const int qq = q0 + l16;
            #pragma unroll
            for (int s = 0; s < 4; ++s) {
                const int keyb = key0 + s * 16 + quad * 4;
                #pragma unroll
                for (int r = 0; r < 4; ++r)
                    sv[s][r] = (keyb + r <= qq) ? sv[s][r] : -1e30f;
            }
        }

        #pragma unroll
        for (int s = 0; s < 4; ++s)
            #pragma unroll
            for (int r = 0; r < 4; ++r) sv[s][r] = exp2f(sv[s][r]);
        #pragma unroll
        for (int s = 0; s < 4; ++s)
            lacc += (sv[s][0] + sv[s][1]) + (sv[s][2] + sv[s][3]);

        // P^T -> per-wave LDS as packed dwords: pw[q=l16][key]
        #pragma unroll
        for (int s = 0; s < 4; ++s) {
            *(unsigned*)&pw[l16 * 72 + s * 16 + quad * 4]     = pk_bf16(sv[s][0], sv[s][1]);
            *(unsigned*)&pw[l16 * 72 + s * 16 + quad * 4 + 2] = pk_bf16(sv[s][2], sv[s][3]);
        }
        asm volatile("" ::: "memory");
        // P^T as B-operand: B[k=key=32h+quad*8+j][n=q=l16]
        bf16x8 pf0 = *(const bf16x8*)&pw[l16 * 72 + quad * 8];
        bf16x8 pf1 = *(const bf16x8*)&pw[l16 * 72 + 32 + quad * 8];
        asm volatile("" ::: "memory");

        #pragma unroll
        for (int dt = 0; dt < 4; ++dt) {
            ot[dt] = __builtin_amdgcn_mfma_f32_16x16x32_bf16(vf[0][dt], pf0, ot[dt], 0, 0, 0);
            ot[dt] = __builtin_amdgcn_mfma_f32_16x16x32_bf16(vf[1][dt], pf1, ot[dt], 0, 0, 0);
        }
    };

    for (int kc = 0; kc < p; ++kc) tile_step(kc, false);
    tile_step(p, true);

    // l reduction: lanes sharing l16 (the 4 quads) hold partial sums
    lacc += __shfl_xor(lacc, 16);
    lacc += __shfl_xor(lacc, 32);
    const float inv = 1.0f / lacc;

    // epilogue: normalize, wave-local LDS transpose O^T -> row-major, store
    #pragma unroll
    for (int dt = 0; dt < 4; ++dt) {
        *(unsigned*)&pw[l16 * 72 + dt * 16 + quad * 4]     = pk_bf16(ot[dt][0] * inv, ot[dt][1] * inv);
        *(unsigned*)&pw[l16 * 72 + dt * 16 + quad * 4 + 2] = pk_bf16(ot[dt][2] * inv, ot[dt][3] * inv);
    }
    asm volatile("" ::: "memory");
    {
        const int qr = lane >> 2, dc = (lane & 3) * 16;
        bf16x8 v0 = *(const bf16x8*)&pw[qr * 72 + dc];
        bf16x8 v1 = *(const bf16x8*)&pw[qr * 72 + dc + 8];
        short* dst = &comb[(rowbase + q0 + qr) * 1024 + hcol + dc];
        *(bf16x8*)dst = v0;
        *(bf16x8*)(dst + 8) = v1;
    }
}

// ---------- launch ----------
extern "C" void kernel_launch(void* const* d_in, const int* in_sizes, int n_in,
                              void* d_out, int out_size, void* d_ws, size_t ws_size,
                              hipStream_t stream)
{
    const float* enc = (const float*)d_in[0];
    const float* Wa  = (const float*)d_in[1];
    const float* ba  = (const float*)d_in[2];
    const float* Wo  = (const float*)d_in[3];
    const float* bo  = (const float*)d_in[4];
    float* out = (float*)d_out;

    char* ws = (char*)d_ws;
    short* Abf  = (short*)ws;                            // 8 MB; reused as comb
    short* comb = Abf;
    short* WtO  = (short*)(ws + ((size_t)8 << 20));      // 2 MB
    short* bbA  = (short*)(ws + ((size_t)10 << 20));     // 6 KB
    short* bbO  = (short*)(ws + ((size_t)10 << 20) + 16384);
    short* WtA  = (short*)(ws + ((size_t)11 << 20));     // 6 MB (dead after gemm1)
    short* Vtw  = (short*)(ws + ((size_t)11 << 20));     // 8 MB (overlaps dead WtA)
    short* qkv  = (short*)(ws + ((size_t)19 << 20));     // 24 MB

    prep_kernel<<<3074, 256, 0, stream>>>(enc, Wa, ba, Wo, bo, Abf, WtA, bbA, WtO, bbO);
    gemm_bt<128, false, true><<<dim3(24, 32), 256, 0, stream>>>(
        Abf, WtA, bbA, qkv, 4096, 3072, 1024);
    vtrans_kernel<<<dim3(32, 32), 256, 0, stream>>>(qkv, Vtw);
    attn_kernel<<<dim3(32, 32), 256, 0, stream>>>(qkv, Vtw, comb);
    gemm_bt<64, true, false><<<dim3(16, 32), 256, 0, stream>>>(
        comb, WtO, bbO, out, 4096, 1024, 1024);
}

// Round 7
// 247.826 us; speedup vs baseline: 1.1150x; 1.1150x over previous
//
#include <hip/hip_runtime.h>
#include <hip/hip_bf16.h>

// ---------- types / helpers ----------
typedef __attribute__((ext_vector_type(8))) short bf16x8;   // 8 bf16 = 4 VGPRs
typedef __attribute__((ext_vector_type(4))) short bf16x4;
typedef __attribute__((ext_vector_type(4))) float f32x4;

__device__ __forceinline__ short f2bf(float f) {
    unsigned u = __float_as_uint(f);
    u += 0x7fff + ((u >> 16) & 1);          // round-to-nearest-even
    return (short)(u >> 16);
}
__device__ __forceinline__ float bf2f(short s) {
    return __uint_as_float(((unsigned)(unsigned short)s) << 16);
}
__device__ __forceinline__ unsigned pk_bf16(float lo, float hi) {
    __hip_bfloat162 t = __float22bfloat162_rn(make_float2(lo, hi));
    unsigned u;
    __builtin_memcpy(&u, &t, 4);
    return u;
}

#define GLOAD_LDS16(gp, lp)                                                            \
    __builtin_amdgcn_global_load_lds(                                                  \
        (const __attribute__((address_space(1))) unsigned*)(gp),                       \
        (__attribute__((address_space(3))) unsigned*)(lp), 16, 0, 0)

#define QK_SCALE 0.180336879f   // (1/sqrt(64)) * log2(e), folded into q at GEMM1
#define MFMA16(a, b, c) __builtin_amdgcn_mfma_f32_16x16x32_bf16((a), (b), (c), 0, 0, 0)

// ---------- fused prep: enc->bf16, biases->bf16, Wa/Wo -> transposed bf16 ----------
__device__ __forceinline__ void tcvt_tile(const float* __restrict__ W, short* __restrict__ Wt,
                                          int K, int N, int bx, int by, int t,
                                          short (*tile)[72]) {
    const int k0 = by * 64, n0 = bx * 64;
    #pragma unroll
    for (int jj = 0; jj < 4; ++jj) {
        int row = jj * 16 + (t >> 4);
        int col = (t & 15) * 4;
        f32x4 v = *(const f32x4*)&W[(size_t)(k0 + row) * N + n0 + col];
        bf16x4 b = {f2bf(v.x), f2bf(v.y), f2bf(v.z), f2bf(v.w)};
        *(bf16x4*)&tile[row][col] = b;
    }
    __syncthreads();
    const int nr = t >> 2, kc = (t & 3) * 16;
    bf16x8 o0, o1;
    #pragma unroll
    for (int j = 0; j < 8; ++j) { o0[j] = tile[kc + j][nr]; o1[j] = tile[kc + 8 + j][nr]; }
    short* dst = &Wt[(size_t)(n0 + nr) * K + k0 + kc];
    *(bf16x8*)dst = o0;
    *(bf16x8*)(dst + 8) = o1;
}

__global__ __launch_bounds__(256) void prep_kernel(
    const float* __restrict__ enc, const float* __restrict__ Wa,
    const float* __restrict__ ba, const float* __restrict__ Wo,
    const float* __restrict__ bo, short* __restrict__ Abf,
    short* __restrict__ WtA, short* __restrict__ bbA,
    short* __restrict__ WtO, short* __restrict__ bbO)
{
    __shared__ alignas(16) short tile[64][72];
    const int id = blockIdx.x, t = threadIdx.x;
    if (id < 2048) {
        const int i = id * 2048 + t * 8;
        f32x4 a = *(const f32x4*)&enc[i];
        f32x4 b = *(const f32x4*)&enc[i + 4];
        bf16x8 o = {f2bf(a.x), f2bf(a.y), f2bf(a.z), f2bf(a.w),
                    f2bf(b.x), f2bf(b.y), f2bf(b.z), f2bf(b.w)};
        *(bf16x8*)&Abf[i] = o;
    } else if (id == 2048) {
        for (int j = t * 8; j < 3072; j += 2048) {
            f32x4 a = *(const f32x4*)&ba[j];
            f32x4 b = *(const f32x4*)&ba[j + 4];
            bf16x8 o = {f2bf(a.x), f2bf(a.y), f2bf(a.z), f2bf(a.w),
                        f2bf(b.x), f2bf(b.y), f2bf(b.z), f2bf(b.w)};
            *(bf16x8*)&bbA[j] = o;
        }
    } else if (id == 2049) {
        if (t < 128) {
            const int j = t * 8;
            f32x4 a = *(const f32x4*)&bo[j];
            f32x4 b = *(const f32x4*)&bo[j + 4];
            bf16x8 o = {f2bf(a.x), f2bf(a.y), f2bf(a.z), f2bf(a.w),
                        f2bf(b.x), f2bf(b.y), f2bf(b.z), f2bf(b.w)};
            *(bf16x8*)&bbO[j] = o;
        }
        __syncthreads();
    } else if (id < 2818) {
        const int lid = id - 2050;
        tcvt_tile(Wa, WtA, 1024, 3072, lid % 48, lid / 48, t, tile);
    } else {
        const int lid = id - 2818;
        tcvt_tile(Wo, WtO, 1024, 1024, lid % 16, lid / 16, t, tile);
    }
}

// ---------- bf16 V slab -> per-head transposed Vt[bh][d][seq] ----------
__global__ __launch_bounds__(256) void vtrans_kernel(const short* __restrict__ qkv,
                                                     short* __restrict__ Vt) {
    __shared__ alignas(16) short T[64][72];
    const int t = threadIdx.x;
    const int seq0 = blockIdx.x * 64;
    const int bh = blockIdx.y, batch = bh >> 4, head = bh & 15;
    #pragma unroll
    for (int jj = 0; jj < 2; ++jj) {
        const int seqr = jj * 32 + (t >> 3);
        const int dcol = (t & 7) * 8;
        bf16x8 v = *(const bf16x8*)&qkv[(size_t)(batch * 2048 + seq0 + seqr) * 3072
                                        + 2048 + head * 64 + dcol];
        #pragma unroll
        for (int j = 0; j < 8; ++j) T[dcol + j][seqr] = v[j];
    }
    __syncthreads();
    #pragma unroll
    for (int jj = 0; jj < 2; ++jj) {
        const int d = jj * 32 + (t >> 3);
        const int sp = (t & 7) * 8;
        bf16x8 v = *(const bf16x8*)&T[d][sp];
        *(bf16x8*)&Vt[((size_t)(batch * 16 + head) * 64 + d) * 2048 + seq0 + sp] = v;
    }
}

// ---------- m97-style BT GEMM: C[M,N] = A[M,K] @ Bt[N,K]^T + bias ----------
template<int BN, bool F32OUT, bool QSCALE>
__global__ __launch_bounds__(256) void gemm_bt(
    const short* __restrict__ A, const short* __restrict__ Bt,
    const short* __restrict__ bias, void* __restrict__ C, int M, int N, int K)
{
    __shared__ alignas(16) short As[128 * 32];
    __shared__ alignas(16) short Bs[BN * 32];

    const int tid = threadIdx.x, w = tid >> 6, lane = tid & 63;
    const int quad = lane >> 4, l16 = lane & 15;
    constexpr int MT = (BN == 128) ? 4 : 2;
    const int wm = (BN == 128) ? (w >> 1) : w;
    const int wn = (BN == 128) ? (w & 1) : 0;
    const int m0 = blockIdx.y * 128, n0 = blockIdx.x * BN;
    const int srow = lane >> 2, scol = (lane & 3) * 8;

    f32x4 acc[MT][4] = {};

    for (int k0 = 0; k0 < K; k0 += 32) {
        __syncthreads();
        #pragma unroll
        for (int jj = 0; jj < 2; ++jj) {
            const int rb = w * 32 + jj * 16;
            GLOAD_LDS16(&A[(size_t)(m0 + rb + srow) * K + k0 + scol], &As[rb * 32]);
        }
        if (BN == 128) {
            #pragma unroll
            for (int jj = 0; jj < 2; ++jj) {
                const int rb = w * 32 + jj * 16;
                GLOAD_LDS16(&Bt[(size_t)(n0 + rb + srow) * K + k0 + scol], &Bs[rb * 32]);
            }
        } else {
            const int rb = w * 16;
            GLOAD_LDS16(&Bt[(size_t)(n0 + rb + srow) * K + k0 + scol], &Bs[rb * 32]);
        }
        __syncthreads();
        bf16x8 af[MT], bfr[4];
        #pragma unroll
        for (int i = 0; i < MT; ++i)
            af[i] = *(const bf16x8*)&As[(wm * (MT * 16) + i * 16 + l16) * 32 + quad * 8];
        #pragma unroll
        for (int i = 0; i < 4; ++i)
            bfr[i] = *(const bf16x8*)&Bs[(wn * 64 + i * 16 + l16) * 32 + quad * 8];
        #pragma unroll
        for (int mt = 0; mt < MT; ++mt)
            #pragma unroll
            for (int nt = 0; nt < 4; ++nt)
                acc[mt][nt] = MFMA16(af[mt], bfr[nt], acc[mt][nt]);
    }

    #pragma unroll
    for (int nt = 0; nt < 4; ++nt) {
        const int col = n0 + wn * 64 + nt * 16 + l16;
        const float bv = bf2f(bias[col]);
        const bool qs = QSCALE && (col < 1024);
        #pragma unroll
        for (int mt = 0; mt < MT; ++mt) {
            const int row = m0 + wm * (MT * 16) + mt * 16 + quad * 4;
            #pragma unroll
            for (int r = 0; r < 4; ++r) {
                float v = acc[mt][nt][r] + bv;
                if (qs) v *= QK_SCALE;
                if (F32OUT) ((float*)C)[(size_t)(row + r) * N + col] = v;
                else        ((short*)C)[(size_t)(row + r) * N + col] = f2bf(v);
            }
        }
    }
}

// ---------- barrier-free causal flash attention: paired 32-row q-tiles ----------
// S^T = K.Q^T; P^T/O^T as in round 6. Block = 128 threads (2 waves); block
// (bh, t) handles q-tiles {t, 63-t} (32 rows each) -> uniform 33 wave-steps.
// K fragments loaded once per kc, shared by both q-tiles. 1024 blocks, 8/CU
// resident (16 waves/CU), flat occupancy, no tail. No min-waves bound (VGPR
// must stay <=128 naturally; forcing caused spills in round 5).
__global__ __launch_bounds__(128) void attn_kernel(
    const short* __restrict__ qkv, const short* __restrict__ Vt, short* __restrict__ comb)
{
    __shared__ alignas(16) short Ps[2][2][16 * 72];   // [wave][tile A/B]

    const int tid = threadIdx.x, w = tid >> 6, lane = tid & 63;
    const int quad = lane >> 4, l16 = lane & 15;
    const int bh = blockIdx.x;
    const int tA = blockIdx.y, tB = 63 - tA;
    const int batch = bh >> 4, head = bh & 15;
    const size_t rowbase = (size_t)batch * 2048;
    const int hcol = head * 64;
    const int q0A = tA * 32 + w * 16, q0B = tB * 32 + w * 16;
    const int diagA = tA >> 1, diagB = tB >> 1;
    const short* Vbase = Vt + (size_t)bh * 64 * 2048;
    short* pwA = &Ps[w][0][0];
    short* pwB = &Ps[w][1][0];

    // Q as B-operand: lane q=l16, d=quad*8+j (+32)
    bf16x8 qfA[2], qfB[2];
    {
        const short* pa = &qkv[(rowbase + q0A + l16) * 3072 + hcol];
        const short* pb = &qkv[(rowbase + q0B + l16) * 3072 + hcol];
        qfA[0] = *(const bf16x8*)(pa + quad * 8);
        qfA[1] = *(const bf16x8*)(pa + 32 + quad * 8);
        qfB[0] = *(const bf16x8*)(pb + quad * 8);
        qfB[1] = *(const bf16x8*)(pb + 32 + quad * 8);
    }

    f32x4 otA[4] = {}, otB[4] = {};
    float laccA = 0.f, laccB = 0.f;

    for (int kc = 0; kc <= diagB; ++kc) {
        const int key0 = kc * 64;
        const bool actA = (kc <= diagA);

        // ---- S^T phase (K loaded once, shared by A and B) ----
        f32x4 svA[4], svB[4];
        #pragma unroll
        for (int s = 0; s < 4; ++s) {
            const short* kp = &qkv[(rowbase + key0 + s * 16 + l16) * 3072 + 1024 + hcol + quad * 8];
            bf16x8 k0 = *(const bf16x8*)kp;
            bf16x8 k1 = *(const bf16x8*)(kp + 32);
            f32x4 a = {0.f, 0.f, 0.f, 0.f};
            a = MFMA16(k0, qfB[0], a);
            a = MFMA16(k1, qfB[1], a);
            svB[s] = a;
            if (actA) {
                f32x4 b = {0.f, 0.f, 0.f, 0.f};
                b = MFMA16(k0, qfA[0], b);
                b = MFMA16(k1, qfA[1], b);
                svA[s] = b;
            }
        }

        // ---- mask (diag tiles only), exp2, l-accumulate, P^T -> LDS ----
        if (kc == diagB) {
            const int qq = q0B + l16;
            #pragma unroll
            for (int s = 0; s < 4; ++s) {
                const int keyb = key0 + s * 16 + quad * 4;
                #pragma unroll
                for (int r = 0; r < 4; ++r)
                    svB[s][r] = (keyb + r <= qq) ? svB[s][r] : -1e30f;
            }
        }
        #pragma unroll
        for (int s = 0; s < 4; ++s) {
            #pragma unroll
            for (int r = 0; r < 4; ++r) svB[s][r] = exp2f(svB[s][r]);
            laccB += (svB[s][0] + svB[s][1]) + (svB[s][2] + svB[s][3]);
            *(unsigned*)&pwB[l16 * 72 + s * 16 + quad * 4]     = pk_bf16(svB[s][0], svB[s][1]);
            *(unsigned*)&pwB[l16 * 72 + s * 16 + quad * 4 + 2] = pk_bf16(svB[s][2], svB[s][3]);
        }
        if (actA) {
            if (kc == diagA) {
                const int qq = q0A + l16;
                #pragma unroll
                for (int s = 0; s < 4; ++s) {
                    const int keyb = key0 + s * 16 + quad * 4;
                    #pragma unroll
                    for (int r = 0; r < 4; ++r)
                        svA[s][r] = (keyb + r <= qq) ? svA[s][r] : -1e30f;
                }
            }
            #pragma unroll
            for (int s = 0; s < 4; ++s) {
                #pragma unroll
                for (int r = 0; r < 4; ++r) svA[s][r] = exp2f(svA[s][r]);
                laccA += (svA[s][0] + svA[s][1]) + (svA[s][2] + svA[s][3]);
                *(unsigned*)&pwA[l16 * 72 + s * 16 + quad * 4]     = pk_bf16(svA[s][0], svA[s][1]);
                *(unsigned*)&pwA[l16 * 72 + s * 16 + quad * 4 + 2] = pk_bf16(svA[s][2], svA[s][3]);
            }
        }
        asm volatile("" ::: "memory");

        // ---- PV phase: V^T loaded once per h, shared by A and B ----
        #pragma unroll
        for (int h = 0; h < 2; ++h) {
            bf16x8 vf[4];
            #pragma unroll
            for (int dt = 0; dt < 4; ++dt)
                vf[dt] = *(const bf16x8*)&Vbase[(size_t)(dt * 16 + l16) * 2048 + key0 + h * 32 + quad * 8];
            bf16x8 pfB = *(const bf16x8*)&pwB[l16 * 72 + h * 32 + quad * 8];
            #pragma unroll
            for (int dt = 0; dt < 4; ++dt)
                otB[dt] = MFMA16(vf[dt], pfB, otB[dt]);
            if (actA) {
                bf16x8 pfA = *(const bf16x8*)&pwA[l16 * 72 + h * 32 + quad * 8];
                #pragma unroll
                for (int dt = 0; dt < 4; ++dt)
                    otA[dt] = MFMA16(vf[dt], pfA, otA[dt]);
            }
        }
        asm volatile("" ::: "memory");
    }

    // ---- l reduction (lanes sharing l16 across quads) + epilogue per tile ----
    laccA += __shfl_xor(laccA, 16);
    laccA += __shfl_xor(laccA, 32);
    laccB += __shfl_xor(laccB, 16);
    laccB += __shfl_xor(laccB, 32);
    const float invA = 1.0f / laccA, invB = 1.0f / laccB;

    #pragma unroll
    for (int dt = 0; dt < 4; ++dt) {
        *(unsigned*)&pwA[l16 * 72 + dt * 16 + quad * 4]     = pk_bf16(otA[dt][0] * invA, otA[dt][1] * invA);
        *(unsigned*)&pwA[l16 * 72 + dt * 16 + quad * 4 + 2] = pk_bf16(otA[dt][2] * invA, otA[dt][3] * invA);
        *(unsigned*)&pwB[l16 * 72 + dt * 16 + quad * 4]     = pk_bf16(otB[dt][0] * invB, otB[dt][1] * invB);
        *(unsigned*)&pwB[l16 * 72 + dt * 16 + quad * 4 + 2] = pk_bf16(otB[dt][2] * invB, otB[dt][3] * invB);
    }
    asm volatile("" ::: "memory");
    {
        const int qr = lane >> 2, dc = (lane & 3) * 16;
        bf16x8 a0 = *(const bf16x8*)&pwA[qr * 72 + dc];
        bf16x8 a1 = *(const bf16x8*)&pwA[qr * 72 + dc + 8];
        short* dstA = &comb[(rowbase + q0A + qr) * 1024 + hcol + dc];
        *(bf16x8*)dstA = a0;
        *(bf16x8*)(dstA + 8) = a1;
        bf16x8 b0 = *(const bf16x8*)&pwB[qr * 72 + dc];
        bf16x8 b1 = *(const bf16x8*)&pwB[qr * 72 + dc + 8];
        short* dstB = &comb[(rowbase + q0B + qr) * 1024 + hcol + dc];
        *(bf16x8*)dstB = b0;
        *(bf16x8*)(dstB + 8) = b1;
    }
}

// ---------- launch ----------
extern "C" void kernel_launch(void* const* d_in, const int* in_sizes, int n_in,
                              void* d_out, int out_size, void* d_ws, size_t ws_size,
                              hipStream_t stream)
{
    const float* enc = (const float*)d_in[0];
    const float* Wa  = (const float*)d_in[1];
    const float* ba  = (const float*)d_in[2];
    const float* Wo  = (const float*)d_in[3];
    const float* bo  = (const float*)d_in[4];
    float* out = (float*)d_out;

    char* ws = (char*)d_ws;
    short* Abf  = (short*)ws;                            // 8 MB; reused as comb
    short* comb = Abf;
    short* WtO  = (short*)(ws + ((size_t)8 << 20));      // 2 MB
    short* bbA  = (short*)(ws + ((size_t)10 << 20));     // 6 KB
    short* bbO  = (short*)(ws + ((size_t)10 << 20) + 16384);
    short* WtA  = (short*)(ws + ((size_t)11 << 20));     // 6 MB (dead after gemm1)
    short* Vtw  = (short*)(ws + ((size_t)11 << 20));     // 8 MB (overlaps dead WtA)
    short* qkv  = (short*)(ws + ((size_t)19 << 20));     // 24 MB

    prep_kernel<<<3074, 256, 0, stream>>>(enc, Wa, ba, Wo, bo, Abf, WtA, bbA, WtO, bbO);
    gemm_bt<128, false, true><<<dim3(24, 32), 256, 0, stream>>>(
        Abf, WtA, bbA, qkv, 4096, 3072, 1024);
    vtrans_kernel<<<dim3(32, 32), 256, 0, stream>>>(qkv, Vtw);
    attn_kernel<<<dim3(32, 32), 128, 0, stream>>>(qkv, Vtw, comb);
    gemm_bt<64, true, false><<<dim3(16, 32), 256, 0, stream>>>(
        comb, WtO, bbO, out, 4096, 1024, 1024);
}